// Round 5
// baseline (85.574 us; speedup 1.0000x reference)
//
#include <hip/hip_runtime.h>
#include <math.h>

#define BATCH    32
#define NHEADS   32
#define KVHEADS  8
#define GRP      4
#define HSZ      128
#define BLKSZ    16
#define BPS      128
#define NTHREADS 512
#define CHUNK    32               // tokens per split (2 cache blocks)
#define NSPLIT   64               // 2048 / CHUNK
#define SCALE    0.08838834764831843f

// ws layout (floats)
#define WSQ_OFF  0                         // [B][32 heads][128] roped*SCALE
#define WSK_OFF  131072                    // [B][8 kvh][128] roped k_new
#define WPM_OFF  163840                    // [B*8*4][NSPLIT]
#define WPL_OFF  229376                    // [B*8*4][NSPLIT]
#define WPO_OFF  294912                    // [B*8*4][NSPLIT][128]
#define WS_FLOATS (WPO_OFF + (size_t)BATCH*KVHEADS*GRP*NSPLIT*HSZ)

// ---------------- pre-kernel: RoPE q (scaled) and k_new into ws ----------------
__global__ __launch_bounds__(NTHREADS) void rope_stage(
    const float* __restrict__ query, const float* __restrict__ k_new,
    const int* __restrict__ ctx_lens,
    float* __restrict__ wsq, float* __restrict__ wsk)
{
    const int b    = blockIdx.x;
    const int tid  = threadIdx.x;
    const int i    = tid & 63;
    const int unit = tid >> 6;          // 0..7
    const float p  = (float)(ctx_lens[b] + 1);
    const float invf = exp2f(-((float)i / 64.0f) * 13.287712379549449f);
    float s_, c_;
    sincosf(p * invf, &s_, &c_);
    for (int h = unit; h < NHEADS; h += 8) {
        const float* qp = query + ((size_t)b * NHEADS + h) * HSZ;
        const float x1 = qp[i], x2 = qp[i + 64];
        wsq[((size_t)b * NHEADS + h) * HSZ + i]      = (x1 * c_ - x2 * s_) * SCALE;
        wsq[((size_t)b * NHEADS + h) * HSZ + i + 64] = (x2 * c_ + x1 * s_) * SCALE;
    }
    const float* kp = k_new + ((size_t)b * KVHEADS + unit) * HSZ;
    const float x1 = kp[i], x2 = kp[i + 64];
    wsk[((size_t)b * KVHEADS + unit) * HSZ + i]      = x1 * c_ - x2 * s_;
    wsk[((size_t)b * KVHEADS + unit) * HSZ + i + 64] = x2 * c_ + x1 * s_;
}

// ---------------- split kernel: one WG per (b, chunk), wave w = kvh w ----------------
__global__ __launch_bounds__(NTHREADS, 8) void pa_partial(
    const float* __restrict__ k_cache,
    const float* __restrict__ v_cache,
    const float* __restrict__ v_new,
    const int*  __restrict__ block_tables,
    const int*  __restrict__ ctx_lens,
    const float* __restrict__ wsq, const float* __restrict__ wsk,
    float* __restrict__ pm, float* __restrict__ pl, float* __restrict__ po)
{
    const int chunk = blockIdx.x & (NSPLIT - 1);
    const int b     = blockIdx.x >> 6;
    const int ctx   = ctx_lens[b];
    const int t0    = chunk * CHUNK;
    if (t0 > ctx) return;

    const int tid  = threadIdx.x;
    const int lane = tid & 63;
    const int w    = tid >> 6;          // wave id == kvh

    __shared__ float q_s[KVHEADS][GRP][HSZ];   // 16 KB, reads are wave-uniform
    __shared__ float sp[KVHEADS][CHUNK][GRP];  // 4 KB, wave-private
    __shared__ int   bt_s[2];

    {   // stage all 32 roped q heads for this batch
        const float4* src = (const float4*)(wsq + (size_t)b * NHEADS * HSZ);
        float4* dst = (float4*)&q_s[0][0][0];
        dst[tid]       = src[tid];
        dst[tid + 512] = src[tid + 512];
    }
    if (tid < 2) bt_s[tid] = block_tables[b * BPS + chunk * 2 + tid];
    __syncthreads();

    const int rg = lane >> 2;           // row in 16-token tile
    const int j  = lane & 3;            // dim-slice lane
    const int jo = j << 2;

    // ---- phase 1: scores (2 tiles = 32 tokens, all loads contiguous per WG) ----
    const float* kb0;
    const float* kb1;
    {
        kb0 = k_cache + (((size_t)bt_s[0] * BLKSZ + rg) * KVHEADS + w) * HSZ + jo;
        if (t0 + rg == ctx)      kb0 = wsk + ((size_t)b * KVHEADS + w) * HSZ + jo;
        kb1 = k_cache + (((size_t)bt_s[1] * BLKSZ + rg) * KVHEADS + w) * HSZ + jo;
        if (t0 + 16 + rg == ctx) kb1 = wsk + ((size_t)b * KVHEADS + w) * HSZ + jo;
    }
    float4 acc0 = make_float4(0.f, 0.f, 0.f, 0.f);
    float4 acc1 = make_float4(0.f, 0.f, 0.f, 0.f);
#pragma unroll
    for (int u = 0; u < 8; ++u) {
        const float4 k0 = *(const float4*)(kb0 + u * 16);
        const float4 k1 = *(const float4*)(kb1 + u * 16);
        const float* qb = &q_s[w][0][u * 16 + jo];
        const float4 qa = *(const float4*)(qb);
        const float4 qg = *(const float4*)(qb + HSZ);
        const float4 qc = *(const float4*)(qb + 2 * HSZ);
        const float4 qd = *(const float4*)(qb + 3 * HSZ);
        acc0.x = fmaf(qa.x,k0.x,fmaf(qa.y,k0.y,fmaf(qa.z,k0.z,fmaf(qa.w,k0.w,acc0.x))));
        acc0.y = fmaf(qg.x,k0.x,fmaf(qg.y,k0.y,fmaf(qg.z,k0.z,fmaf(qg.w,k0.w,acc0.y))));
        acc0.z = fmaf(qc.x,k0.x,fmaf(qc.y,k0.y,fmaf(qc.z,k0.z,fmaf(qc.w,k0.w,acc0.z))));
        acc0.w = fmaf(qd.x,k0.x,fmaf(qd.y,k0.y,fmaf(qd.z,k0.z,fmaf(qd.w,k0.w,acc0.w))));
        acc1.x = fmaf(qa.x,k1.x,fmaf(qa.y,k1.y,fmaf(qa.z,k1.z,fmaf(qa.w,k1.w,acc1.x))));
        acc1.y = fmaf(qg.x,k1.x,fmaf(qg.y,k1.y,fmaf(qg.z,k1.z,fmaf(qg.w,k1.w,acc1.y))));
        acc1.z = fmaf(qc.x,k1.x,fmaf(qc.y,k1.y,fmaf(qc.z,k1.z,fmaf(qc.w,k1.w,acc1.z))));
        acc1.w = fmaf(qd.x,k1.x,fmaf(qd.y,k1.y,fmaf(qd.z,k1.z,fmaf(qd.w,k1.w,acc1.w))));
    }
    acc0.x += __shfl_xor(acc0.x,1); acc0.x += __shfl_xor(acc0.x,2);
    acc0.y += __shfl_xor(acc0.y,1); acc0.y += __shfl_xor(acc0.y,2);
    acc0.z += __shfl_xor(acc0.z,1); acc0.z += __shfl_xor(acc0.z,2);
    acc0.w += __shfl_xor(acc0.w,1); acc0.w += __shfl_xor(acc0.w,2);
    acc1.x += __shfl_xor(acc1.x,1); acc1.x += __shfl_xor(acc1.x,2);
    acc1.y += __shfl_xor(acc1.y,1); acc1.y += __shfl_xor(acc1.y,2);
    acc1.z += __shfl_xor(acc1.z,1); acc1.z += __shfl_xor(acc1.z,2);
    acc1.w += __shfl_xor(acc1.w,1); acc1.w += __shfl_xor(acc1.w,2);
    if (j == 0) {
        *(float4*)&sp[w][rg][0]      = acc0;
        *(float4*)&sp[w][16 + rg][0] = acc1;
    }
    // no barrier: sp[w] is wave-private

    // ---- phase 2: softmax over the 32 chunk tokens (wave-local) ----
    const int nvalid = min(CHUNK, ctx - t0 + 1);
    float4 s = *(const float4*)&sp[w][lane & 31][0];
    if ((lane & 31) >= nvalid) s = make_float4(-INFINITY, -INFINITY, -INFINITY, -INFINITY);
    float4 mx = s;
#pragma unroll
    for (int hop = 1; hop <= 16; hop <<= 1) {
        mx.x = fmaxf(mx.x, __shfl_xor(mx.x, hop));
        mx.y = fmaxf(mx.y, __shfl_xor(mx.y, hop));
        mx.z = fmaxf(mx.z, __shfl_xor(mx.z, hop));
        mx.w = fmaxf(mx.w, __shfl_xor(mx.w, hop));
    }
    float4 pr;
    pr.x = __expf(s.x - mx.x); pr.y = __expf(s.y - mx.y);
    pr.z = __expf(s.z - mx.z); pr.w = __expf(s.w - mx.w);
    float4 ls = pr;
#pragma unroll
    for (int hop = 1; hop <= 16; hop <<= 1) {
        ls.x += __shfl_xor(ls.x, hop);
        ls.y += __shfl_xor(ls.y, hop);
        ls.z += __shfl_xor(ls.z, hop);
        ls.w += __shfl_xor(ls.w, hop);
    }
    if (lane < 32) *(float4*)&sp[w][lane][0] = pr;
    if (lane == 0) {
        const size_t hd = ((size_t)(b * KVHEADS + w)) * GRP;
        pm[(hd + 0) * NSPLIT + chunk] = mx.x; pl[(hd + 0) * NSPLIT + chunk] = ls.x;
        pm[(hd + 1) * NSPLIT + chunk] = mx.y; pl[(hd + 1) * NSPLIT + chunk] = ls.y;
        pm[(hd + 2) * NSPLIT + chunk] = mx.z; pl[(hd + 2) * NSPLIT + chunk] = ls.z;
        pm[(hd + 3) * NSPLIT + chunk] = mx.w; pl[(hd + 3) * NSPLIT + chunk] = ls.w;
    }

    // ---- phase 3: PV, half-wave per parity, contiguous V rows ----
    const int hh = lane >> 5;
    const int d0 = (lane & 31) << 2;
    float4 o0 = make_float4(0,0,0,0), o1 = o0, o2 = o0, o3 = o0;
    for (int t = hh; t < nvalid; t += 2) {
        const int blk = bt_s[t >> 4];
        const float* vb = v_cache + (((size_t)blk * BLKSZ + (t & 15)) * KVHEADS + w) * HSZ;
        if (t0 + t == ctx) vb = v_new + ((size_t)b * KVHEADS + w) * HSZ;
        const float4 vv = *(const float4*)(vb + d0);
        const float4 pv = *(const float4*)&sp[w][t][0];
        o0.x += pv.x*vv.x; o0.y += pv.x*vv.y; o0.z += pv.x*vv.z; o0.w += pv.x*vv.w;
        o1.x += pv.y*vv.x; o1.y += pv.y*vv.y; o1.z += pv.y*vv.z; o1.w += pv.y*vv.w;
        o2.x += pv.z*vv.x; o2.y += pv.z*vv.y; o2.z += pv.z*vv.z; o2.w += pv.z*vv.w;
        o3.x += pv.w*vv.x; o3.y += pv.w*vv.y; o3.z += pv.w*vv.z; o3.w += pv.w*vv.w;
    }
    o0.x += __shfl_xor(o0.x,32); o0.y += __shfl_xor(o0.y,32); o0.z += __shfl_xor(o0.z,32); o0.w += __shfl_xor(o0.w,32);
    o1.x += __shfl_xor(o1.x,32); o1.y += __shfl_xor(o1.y,32); o1.z += __shfl_xor(o1.z,32); o1.w += __shfl_xor(o1.w,32);
    o2.x += __shfl_xor(o2.x,32); o2.y += __shfl_xor(o2.y,32); o2.z += __shfl_xor(o2.z,32); o2.w += __shfl_xor(o2.w,32);
    o3.x += __shfl_xor(o3.x,32); o3.y += __shfl_xor(o3.y,32); o3.z += __shfl_xor(o3.z,32); o3.w += __shfl_xor(o3.w,32);
    if (hh == 0) {
        const size_t hd = ((size_t)(b * KVHEADS + w)) * GRP;
        *(float4*)&po[((hd + 0) * NSPLIT + chunk) * HSZ + d0] = o0;
        *(float4*)&po[((hd + 1) * NSPLIT + chunk) * HSZ + d0] = o1;
        *(float4*)&po[((hd + 2) * NSPLIT + chunk) * HSZ + d0] = o2;
        *(float4*)&po[((hd + 3) * NSPLIT + chunk) * HSZ + d0] = o3;
    }
}

// ---------------- reduce kernel: one WG per (b, kvh) ----------------
__global__ __launch_bounds__(NTHREADS) void pa_reduce(
    const int*  __restrict__ ctx_lens,
    const float* __restrict__ pm, const float* __restrict__ pl,
    const float* __restrict__ po, float* __restrict__ out)
{
    const int b    = blockIdx.x >> 3;
    const int kvh  = blockIdx.x & 7;
    const int ctx  = ctx_lens[b];
    const int nact = (ctx >> 5) + 1;
    const int tid  = threadIdx.x;
    const int g    = tid >> 7;
    const int d    = tid & 127;
    const size_t idx = (((size_t)(b * KVHEADS + kvh)) * GRP + g) * NSPLIT;

    float M = -INFINITY;
    for (int p = 0; p < nact; ++p) M = fmaxf(M, pm[idx + p]);
    float L = 0.f, O = 0.f;
    for (int p = 0; p < nact; ++p) {
        const float wgt = __expf(pm[idx + p] - M);
        L += pl[idx + p] * wgt;
        O += po[(idx + p) * HSZ + d] * wgt;
    }
    out[((size_t)b * NHEADS + kvh * GRP + g) * HSZ + d] = O / L;
}

// ---------------- fallback: single kernel (if ws too small) ----------------
__device__ __forceinline__ float hsum32(float v) {
    v += __shfl_xor(v, 1); v += __shfl_xor(v, 2); v += __shfl_xor(v, 4);
    v += __shfl_xor(v, 8); v += __shfl_xor(v, 16);
    return v;
}
__device__ __forceinline__ void proc_row_f(const float4 kv, const float4 vv,
                                           const float4* qf, float* m, float* l, float4* o) {
    float s[GRP];
#pragma unroll
    for (int g = 0; g < GRP; ++g)
        s[g] = qf[g].x*kv.x + qf[g].y*kv.y + qf[g].z*kv.z + qf[g].w*kv.w;
#pragma unroll
    for (int g = 0; g < GRP; ++g) s[g] = hsum32(s[g]);
#pragma unroll
    for (int g = 0; g < GRP; ++g) {
        const float sc = s[g] * SCALE;
        const float mn = fmaxf(m[g], sc);
        const float cf = __expf(m[g] - mn);
        const float pp = __expf(sc - mn);
        l[g] = l[g] * cf + pp;
        o[g].x = o[g].x*cf + pp*vv.x; o[g].y = o[g].y*cf + pp*vv.y;
        o[g].z = o[g].z*cf + pp*vv.z; o[g].w = o[g].w*cf + pp*vv.w;
        m[g] = mn;
    }
}
__global__ __launch_bounds__(NTHREADS) void paged_attn_single(
    const float* __restrict__ query, const float* __restrict__ k_new,
    const float* __restrict__ v_new, const float* __restrict__ k_cache,
    const float* __restrict__ v_cache, const int* __restrict__ block_tables,
    const int* __restrict__ ctx_lens, float* __restrict__ out)
{
    const int wg = blockIdx.x, b = wg >> 3, kvh = wg & 7;
    const int tid = threadIdx.x, sub = tid & 31, proc = tid >> 5;
    const int ctx = ctx_lens[b];
    __shared__ float q_s[GRP][HSZ];
    __shared__ float kn_s[HSZ];
    __shared__ int   bt_s[BPS];
    __shared__ float m_s[16][GRP];
    __shared__ float l_s[16][GRP];
    __shared__ float o_s[16][GRP][HSZ];
    {
        const float p = (float)(ctx + 1);
        if (tid < 320) {
            const int   i    = tid & 63;
            const float invf = exp2f(-((float)i / 64.0f) * 13.287712379549449f);
            float s_, c_;
            sincosf(p * invf, &s_, &c_);
            if (tid < 256) {
                const int g = tid >> 6;
                const float* qp = query + ((size_t)b * NHEADS + kvh * GRP + g) * HSZ;
                const float x1 = qp[i], x2 = qp[i + 64];
                q_s[g][i] = x1*c_ - x2*s_; q_s[g][i+64] = x2*c_ + x1*s_;
            } else {
                const float* kp = k_new + ((size_t)b * KVHEADS + kvh) * HSZ;
                const float x1 = kp[i], x2 = kp[i + 64];
                kn_s[i] = x1*c_ - x2*s_; kn_s[i+64] = x2*c_ + x1*s_;
            }
        } else if (tid < 448) {
            bt_s[tid - 320] = block_tables[b * BPS + (tid - 320)];
        }
    }
    __syncthreads();
    const int d0 = sub << 2;
    float4 qf[GRP];
#pragma unroll
    for (int g = 0; g < GRP; ++g) qf[g] = *(const float4*)&q_s[g][d0];
    float m[GRP], l[GRP]; float4 o[GRP];
#pragma unroll
    for (int g = 0; g < GRP; ++g) { m[g] = -INFINITY; l[g] = 0.f; o[g] = make_float4(0,0,0,0); }
    for (int t = proc; t < ctx; t += 16) {
        const int blk = bt_s[t >> 4];
        const size_t a0 = (((size_t)blk*BLKSZ + (t & 15))*KVHEADS + kvh)*HSZ + d0;
        proc_row_f(*(const float4*)(k_cache + a0), *(const float4*)(v_cache + a0), qf, m, l, o);
    }
    if (proc == (ctx & 15)) {
        proc_row_f(*(const float4*)&kn_s[d0],
                   *(const float4*)(v_new + ((size_t)b*KVHEADS + kvh)*HSZ + d0), qf, m, l, o);
    }
    if (sub == 0) {
#pragma unroll
        for (int g = 0; g < GRP; ++g) { m_s[proc][g] = m[g]; l_s[proc][g] = l[g]; }
    }
#pragma unroll
    for (int g = 0; g < GRP; ++g) *(float4*)&o_s[proc][g][d0] = o[g];
    __syncthreads();
    {
        const int g = tid >> 7, d = tid & 127;
        float mt = -INFINITY;
#pragma unroll
        for (int p = 0; p < 16; ++p) mt = fmaxf(mt, m_s[p][g]);
        float lt = 0.f, ot = 0.f;
#pragma unroll
        for (int p = 0; p < 16; ++p) {
            const float wgt = __expf(m_s[p][g] - mt);
            lt += l_s[p][g]*wgt; ot += o_s[p][g][d]*wgt;
        }
        out[((size_t)b*NHEADS + kvh*GRP + g)*HSZ + d] = ot / lt;
    }
}

extern "C" void kernel_launch(void* const* d_in, const int* in_sizes, int n_in,
                              void* d_out, int out_size, void* d_ws, size_t ws_size,
                              hipStream_t stream) {
    const float* query        = (const float*)d_in[0];
    const float* k_new        = (const float*)d_in[1];
    const float* v_new        = (const float*)d_in[2];
    const float* k_cache      = (const float*)d_in[3];
    const float* v_cache      = (const float*)d_in[4];
    const int*   block_tables = (const int*)d_in[5];
    const int*   ctx_lens     = (const int*)d_in[6];
    float*       out          = (float*)d_out;

    if (ws_size >= WS_FLOATS * sizeof(float)) {
        float* ws  = (float*)d_ws;
        float* wsq = ws + WSQ_OFF;
        float* wsk = ws + WSK_OFF;
        float* pm  = ws + WPM_OFF;
        float* pl  = ws + WPL_OFF;
        float* po  = ws + WPO_OFF;
        rope_stage<<<dim3(BATCH), dim3(NTHREADS), 0, stream>>>(
            query, k_new, ctx_lens, wsq, wsk);
        pa_partial<<<dim3(BATCH * NSPLIT), dim3(NTHREADS), 0, stream>>>(
            k_cache, v_cache, v_new, block_tables, ctx_lens, wsq, wsk, pm, pl, po);
        pa_reduce<<<dim3(BATCH * KVHEADS), dim3(NTHREADS), 0, stream>>>(
            ctx_lens, pm, pl, po, out);
    } else {
        paged_attn_single<<<dim3(BATCH * KVHEADS), dim3(NTHREADS), 0, stream>>>(
            query, k_new, v_new, k_cache, v_cache, block_tables, ctx_lens, out);
    }
}